// Round 2
// baseline (6631.092 us; speedup 1.0000x reference)
//
#include <hip/hip_runtime.h>

#define N_NODES 50000
#define N_EDGES 800000
#define F_IN    512
#define F_HID   256
#define F_OUT   60

// ---------------- degree / normalization ----------------
__global__ void k_deg_init(int* __restrict__ deg) {
    int i = blockIdx.x * blockDim.x + threadIdx.x;
    if (i < N_NODES) deg[i] = 1;           // +1 for self loop
}
__global__ void k_deg_count(const int* __restrict__ dst, int* __restrict__ deg) {
    int i = blockIdx.x * blockDim.x + threadIdx.x;
    if (i < N_EDGES) atomicAdd(&deg[dst[i]], 1);
}
__global__ void k_dis(const int* __restrict__ deg, float* __restrict__ dis) {
    int i = blockIdx.x * blockDim.x + threadIdx.x;
    if (i < N_NODES) dis[i] = rsqrtf((float)deg[i]);
}

// ---------------- fp32 tiled GEMM: C = A(MxK) @ B(KxN), 128x128 tile ----------------
// 256 threads, 8x8 acc per thread as 2x2 grid of 4x4 micro-tiles.
// A staged k-major (transposed) so fragment reads are ds_read_b128.
// Writes H = C always. If FUSE_AGG: AGG[m][n] = bias[n] + C[m][n]*dis[m]^2.
// RELU_A applies relu on A load.
template<bool RELU_A, bool FUSE_AGG>
__global__ __launch_bounds__(256)
void k_gemm128(const float* __restrict__ A, const float* __restrict__ B,
               float* __restrict__ H, float* __restrict__ AGG,
               const float* __restrict__ bias, const float* __restrict__ dis,
               int M, int K, int Nn)
{
    __shared__ float Ast[16][132];  // [k][m], +4 pad: transposed-store 2-way (free)
    __shared__ float Bs[16][132];   // [k][n]

    const int tid = threadIdx.x;
    const int tx = tid & 15, ty = tid >> 4;
    const int m0 = blockIdx.y * 128, n0 = blockIdx.x * 128;

    // A: 128 rows x 16 k. Each thread: row=tid>>1, 8 consecutive k at (tid&1)*8.
    const int ar = tid >> 1, ac = (tid & 1) * 8;
    // B: 16 rows x 128 n. Each thread: row=tid>>4, 8 consecutive n at (tid&15)*8.
    const int br = tid >> 4, bc = (tid & 15) * 8;

    float acc[2][2][4][4] = {};

    for (int k0 = 0; k0 < K; k0 += 16) {
        // ---- stage A (transposed) ----
        {
            float4 v0 = make_float4(0.f, 0.f, 0.f, 0.f);
            float4 v1 = make_float4(0.f, 0.f, 0.f, 0.f);
            int gm = m0 + ar;
            if (gm < M) {
                const float* ap = A + (size_t)gm * K + k0 + ac;
                v0 = *(const float4*)(ap);
                v1 = *(const float4*)(ap + 4);
                if (RELU_A) {
                    v0.x = fmaxf(v0.x, 0.f); v0.y = fmaxf(v0.y, 0.f);
                    v0.z = fmaxf(v0.z, 0.f); v0.w = fmaxf(v0.w, 0.f);
                    v1.x = fmaxf(v1.x, 0.f); v1.y = fmaxf(v1.y, 0.f);
                    v1.z = fmaxf(v1.z, 0.f); v1.w = fmaxf(v1.w, 0.f);
                }
            }
            Ast[ac + 0][ar] = v0.x; Ast[ac + 1][ar] = v0.y;
            Ast[ac + 2][ar] = v0.z; Ast[ac + 3][ar] = v0.w;
            Ast[ac + 4][ar] = v1.x; Ast[ac + 5][ar] = v1.y;
            Ast[ac + 6][ar] = v1.z; Ast[ac + 7][ar] = v1.w;
        }
        // ---- stage B ----
        {
            int gk = k0 + br;
            const float* bp = B + (size_t)gk * Nn;
#pragma unroll
            for (int h = 0; h < 2; ++h) {
                int gn = n0 + bc + h * 4;
                float4 v;
                if (gn + 3 < Nn) {
                    v = *(const float4*)(bp + gn);
                } else {
                    v.x = (gn + 0 < Nn) ? bp[gn + 0] : 0.f;
                    v.y = (gn + 1 < Nn) ? bp[gn + 1] : 0.f;
                    v.z = (gn + 2 < Nn) ? bp[gn + 2] : 0.f;
                    v.w = (gn + 3 < Nn) ? bp[gn + 3] : 0.f;
                }
                *(float4*)&Bs[br][bc + h * 4] = v;
            }
        }
        __syncthreads();

#pragma unroll
        for (int kk = 0; kk < 16; ++kk) {
            float4 a0 = *(const float4*)&Ast[kk][ty * 4];
            float4 a1 = *(const float4*)&Ast[kk][64 + ty * 4];
            float4 b0 = *(const float4*)&Bs[kk][tx * 4];
            float4 b1 = *(const float4*)&Bs[kk][64 + tx * 4];
            float av[2][4] = {{a0.x, a0.y, a0.z, a0.w}, {a1.x, a1.y, a1.z, a1.w}};
            float bv[2][4] = {{b0.x, b0.y, b0.z, b0.w}, {b1.x, b1.y, b1.z, b1.w}};
#pragma unroll
            for (int mi = 0; mi < 2; ++mi)
#pragma unroll
                for (int i = 0; i < 4; ++i)
#pragma unroll
                    for (int ni = 0; ni < 2; ++ni)
#pragma unroll
                        for (int j = 0; j < 4; ++j)
                            acc[mi][ni][i][j] = fmaf(av[mi][i], bv[ni][j], acc[mi][ni][i][j]);
        }
        __syncthreads();
    }

    // ---- epilogue ----
#pragma unroll
    for (int mi = 0; mi < 2; ++mi)
#pragma unroll
        for (int i = 0; i < 4; ++i) {
            int gm = m0 + mi * 64 + ty * 4 + i;
            if (gm >= M) continue;
            float d2 = 0.f;
            if (FUSE_AGG) { float dv = dis[gm]; d2 = dv * dv; }
#pragma unroll
            for (int ni = 0; ni < 2; ++ni) {
                int gn = n0 + ni * 64 + tx * 4;
                if (gn >= Nn) continue;
                float* hp = H + (size_t)gm * Nn + gn;
                float* gp = FUSE_AGG ? (AGG + (size_t)gm * Nn + gn) : nullptr;
                if (gn + 3 < Nn) {
                    float4 c = make_float4(acc[mi][ni][i][0], acc[mi][ni][i][1],
                                           acc[mi][ni][i][2], acc[mi][ni][i][3]);
                    *(float4*)hp = c;
                    if (FUSE_AGG) {
                        float4 o;
                        o.x = fmaf(c.x, d2, bias[gn + 0]);
                        o.y = fmaf(c.y, d2, bias[gn + 1]);
                        o.z = fmaf(c.z, d2, bias[gn + 2]);
                        o.w = fmaf(c.w, d2, bias[gn + 3]);
                        *(float4*)gp = o;
                    }
                } else {
#pragma unroll
                    for (int j = 0; j < 4; ++j) {
                        if (gn + j < Nn) {
                            float c = acc[mi][ni][i][j];
                            hp[j] = c;
                            if (FUSE_AGG) gp[j] = fmaf(c, d2, bias[gn + j]);
                        }
                    }
                }
            }
        }
}

// init AGG = bias + H*dis^2 (layer-2 path, separate pass to avoid intra-kernel race)
__global__ void k_init_agg256(const float* __restrict__ H, const float* __restrict__ bias,
                              const float* __restrict__ dis, float* __restrict__ AGG)
{
    int i = blockIdx.x * blockDim.x + threadIdx.x;  // over N_NODES*64 float4s
    if (i < N_NODES * 64) {
        int m = i >> 6, c4 = i & 63;
        float dv = dis[m]; float d2 = dv * dv;
        float4 h = ((const float4*)H)[i];
        float4 b = ((const float4*)bias)[c4];
        float4 o;
        o.x = fmaf(h.x, d2, b.x); o.y = fmaf(h.y, d2, b.y);
        o.z = fmaf(h.z, d2, b.z); o.w = fmaf(h.w, d2, b.w);
        ((float4*)AGG)[i] = o;
    }
}

// ---------------- edge scatter (push, atomics) ----------------
__global__ __launch_bounds__(256)
void k_scatter256(const float* __restrict__ H, const int* __restrict__ src,
                  const int* __restrict__ dst, const float* __restrict__ dis,
                  float* __restrict__ agg)
{
    int gid = blockIdx.x * blockDim.x + threadIdx.x;
    int w = gid >> 6, lane = gid & 63;
    int nw = (gridDim.x * blockDim.x) >> 6;
    for (int e = w; e < N_EDGES; e += nw) {
        int s = src[e], d = dst[e];
        float nrm = dis[s] * dis[d];
        float4 v = ((const float4*)(H + (size_t)s * 256))[lane];
        float* o = agg + (size_t)d * 256 + lane * 4;
        unsafeAtomicAdd(o + 0, v.x * nrm);
        unsafeAtomicAdd(o + 1, v.y * nrm);
        unsafeAtomicAdd(o + 2, v.z * nrm);
        unsafeAtomicAdd(o + 3, v.w * nrm);
    }
}

__global__ __launch_bounds__(256)
void k_scatter60(const float* __restrict__ H3, const int* __restrict__ src,
                 const int* __restrict__ dst, const float* __restrict__ dis,
                 float* __restrict__ out)
{
    int gid = blockIdx.x * blockDim.x + threadIdx.x;
    int e0 = gid >> 4, lane = gid & 15;   // 16 threads/edge, 15 active (15*4 = 60 floats)
    int ne = (gridDim.x * blockDim.x) >> 4;
    for (int e = e0; e < N_EDGES; e += ne) {
        if (lane < 15) {
            int s = src[e], d = dst[e];
            float nrm = dis[s] * dis[d];
            float4 v = ((const float4*)(H3 + (size_t)s * 60))[lane];
            float* o = out + (size_t)d * 60 + lane * 4;
            unsafeAtomicAdd(o + 0, v.x * nrm);
            unsafeAtomicAdd(o + 1, v.y * nrm);
            unsafeAtomicAdd(o + 2, v.z * nrm);
            unsafeAtomicAdd(o + 3, v.w * nrm);
        }
    }
}

// ---------------- launch ----------------
extern "C" void kernel_launch(void* const* d_in, const int* in_sizes, int n_in,
                              void* d_out, int out_size, void* d_ws, size_t ws_size,
                              hipStream_t stream)
{
    const float* x  = (const float*)d_in[0];
    const int*   ei = (const int*)d_in[1];
    // d_in[2] = batch (identity pooling; unused)
    const float* W1 = (const float*)d_in[3];
    const float* b1 = (const float*)d_in[4];
    const float* W2 = (const float*)d_in[5];
    const float* b2 = (const float*)d_in[6];
    const float* W3 = (const float*)d_in[7];
    const float* b3 = (const float*)d_in[8];
    float* out = (float*)d_out;

    const int* src = ei;
    const int* dst = ei + N_EDGES;

    char* ws = (char*)d_ws;
    int*   deg  = (int*)(ws + 0);                               // 200,000 B
    float* dis  = (float*)(ws + 200704);                        // 200,000 B
    float* bufA = (float*)(ws + 401408);                        // 51.2 MB
    float* bufB = (float*)(ws + 401408 + 51200000);             // 51.2 MB
    float* H3   = (float*)(ws + 401408 + 2 * 51200000);         // 12.0 MB

    // normalization (shared across all 3 convs)
    k_deg_init<<<(N_NODES + 255) / 256, 256, 0, stream>>>(deg);
    k_deg_count<<<(N_EDGES + 255) / 256, 256, 0, stream>>>(dst, deg);
    k_dis<<<(N_NODES + 255) / 256, 256, 0, stream>>>(deg, dis);

    dim3 blk(256);
    const int MB = (N_NODES + 127) / 128;   // 391

    // layer 1: H1 = x @ W1 ; agg1 = b1 + H1*dis^2 ; += edges
    k_gemm128<false, true><<<dim3(2, MB), blk, 0, stream>>>(x, W1, bufA, bufB, b1, dis,
                                                            N_NODES, F_IN, F_HID);
    k_scatter256<<<2048, 256, 0, stream>>>(bufA, src, dst, dis, bufB);

    // layer 2: H2 = relu(agg1) @ W2 ; agg2 = b2 + H2*dis^2 ; += edges
    k_gemm128<true, false><<<dim3(2, MB), blk, 0, stream>>>(bufB, W2, bufA, nullptr, nullptr, nullptr,
                                                            N_NODES, F_HID, F_HID);
    k_init_agg256<<<(N_NODES * 64 + 255) / 256, 256, 0, stream>>>(bufA, b2, dis, bufB);
    k_scatter256<<<2048, 256, 0, stream>>>(bufA, src, dst, dis, bufB);

    // layer 3 (pool is identity): H3 = relu(agg2) @ W3 ; out = b3 + H3*dis^2 ; += edges
    k_gemm128<true, true><<<dim3(1, MB), blk, 0, stream>>>(bufB, W3, H3, out, b3, dis,
                                                           N_NODES, F_HID, F_OUT);
    k_scatter60<<<2048, 256, 0, stream>>>(H3, src, dst, dis, out);
}

// Round 3
// 869.472 us; speedup vs baseline: 7.6266x; 7.6266x over previous
//
#include <hip/hip_runtime.h>

#define N_NODES 50000
#define N_EDGES 800000
#define F_IN    512
#define F_HID   256
#define F_OUT   60
#define SCAN_BLOCKS ((N_NODES + 255) / 256)   // 196

// ---------------- degree / CSR build ----------------
__global__ void k_cnt_zero(int* __restrict__ cnt) {
    int i = blockIdx.x * blockDim.x + threadIdx.x;
    if (i < N_NODES) cnt[i] = 0;
}
__global__ void k_deg_count(const int* __restrict__ dst, int* __restrict__ cnt) {
    int i = blockIdx.x * blockDim.x + threadIdx.x;
    if (i < N_EDGES) atomicAdd(&cnt[dst[i]], 1);
}
__global__ void k_dis(const int* __restrict__ cnt, float* __restrict__ dis) {
    int i = blockIdx.x * blockDim.x + threadIdx.x;
    if (i < N_NODES) dis[i] = rsqrtf((float)(cnt[i] + 1));   // +1 self loop
}

// exclusive scan, 3 kernels (256/block)
__global__ void k_scan1(const int* __restrict__ cnt, int* __restrict__ scanned,
                        int* __restrict__ blocksum) {
    __shared__ int tmp[256];
    int i = blockIdx.x * 256 + threadIdx.x;
    int v = (i < N_NODES) ? cnt[i] : 0;
    tmp[threadIdx.x] = v;
    __syncthreads();
    for (int off = 1; off < 256; off <<= 1) {
        int t = (threadIdx.x >= off) ? tmp[threadIdx.x - off] : 0;
        __syncthreads();
        tmp[threadIdx.x] += t;
        __syncthreads();
    }
    if (i < N_NODES) scanned[i] = tmp[threadIdx.x] - v;   // exclusive
    if (threadIdx.x == 255) blocksum[blockIdx.x] = tmp[255];
}
__global__ void k_scan2(const int* __restrict__ blocksum, int* __restrict__ blockoff) {
    __shared__ int tmp[256];
    int v = (threadIdx.x < SCAN_BLOCKS) ? blocksum[threadIdx.x] : 0;
    tmp[threadIdx.x] = v;
    __syncthreads();
    for (int off = 1; off < 256; off <<= 1) {
        int t = (threadIdx.x >= off) ? tmp[threadIdx.x - off] : 0;
        __syncthreads();
        tmp[threadIdx.x] += t;
        __syncthreads();
    }
    if (threadIdx.x < SCAN_BLOCKS) blockoff[threadIdx.x] = tmp[threadIdx.x] - v;
}
__global__ void k_scan3(const int* __restrict__ scanned, const int* __restrict__ blockoff,
                        int* __restrict__ row_ptr, int* __restrict__ cursor) {
    int i = blockIdx.x * 256 + threadIdx.x;
    if (i < N_NODES) {
        int rp = scanned[i] + blockoff[blockIdx.x];
        row_ptr[i] = rp;
        cursor[i] = rp;
    }
    if (i == 0) row_ptr[N_NODES] = N_EDGES;
}
__global__ void k_fill(const int* __restrict__ src, const int* __restrict__ dst,
                       int* __restrict__ cursor, int* __restrict__ esrc) {
    int e = blockIdx.x * blockDim.x + threadIdx.x;
    if (e < N_EDGES) {
        int pos = atomicAdd(&cursor[dst[e]], 1);
        esrc[pos] = src[e];
    }
}

// ---------------- fp32 tiled GEMM: C = A(MxK) @ B(KxN), 128x128 tile ----------------
__global__ __launch_bounds__(256)
void k_gemm128(const float* __restrict__ A, const float* __restrict__ B,
               float* __restrict__ H, int M, int K, int Nn)
{
    __shared__ float Ast[16][132];  // [k][m] transposed
    __shared__ float Bs[16][132];   // [k][n]

    const int tid = threadIdx.x;
    const int tx = tid & 15, ty = tid >> 4;
    const int m0 = blockIdx.y * 128, n0 = blockIdx.x * 128;

    const int ar = tid >> 1, ac = (tid & 1) * 8;
    const int br = tid >> 4, bc = (tid & 15) * 8;

    float acc[2][2][4][4] = {};

    for (int k0 = 0; k0 < K; k0 += 16) {
        {
            float4 v0 = make_float4(0.f, 0.f, 0.f, 0.f);
            float4 v1 = make_float4(0.f, 0.f, 0.f, 0.f);
            int gm = m0 + ar;
            if (gm < M) {
                const float* ap = A + (size_t)gm * K + k0 + ac;
                v0 = *(const float4*)(ap);
                v1 = *(const float4*)(ap + 4);
            }
            Ast[ac + 0][ar] = v0.x; Ast[ac + 1][ar] = v0.y;
            Ast[ac + 2][ar] = v0.z; Ast[ac + 3][ar] = v0.w;
            Ast[ac + 4][ar] = v1.x; Ast[ac + 5][ar] = v1.y;
            Ast[ac + 6][ar] = v1.z; Ast[ac + 7][ar] = v1.w;
        }
        {
            int gk = k0 + br;
            const float* bp = B + (size_t)gk * Nn;
#pragma unroll
            for (int h = 0; h < 2; ++h) {
                int gn = n0 + bc + h * 4;
                float4 v;
                if (gn + 3 < Nn) {
                    v = *(const float4*)(bp + gn);
                } else {
                    v.x = (gn + 0 < Nn) ? bp[gn + 0] : 0.f;
                    v.y = (gn + 1 < Nn) ? bp[gn + 1] : 0.f;
                    v.z = (gn + 2 < Nn) ? bp[gn + 2] : 0.f;
                    v.w = (gn + 3 < Nn) ? bp[gn + 3] : 0.f;
                }
                *(float4*)&Bs[br][bc + h * 4] = v;
            }
        }
        __syncthreads();

#pragma unroll
        for (int kk = 0; kk < 16; ++kk) {
            float4 a0 = *(const float4*)&Ast[kk][ty * 4];
            float4 a1 = *(const float4*)&Ast[kk][64 + ty * 4];
            float4 b0 = *(const float4*)&Bs[kk][tx * 4];
            float4 b1 = *(const float4*)&Bs[kk][64 + tx * 4];
            float av[2][4] = {{a0.x, a0.y, a0.z, a0.w}, {a1.x, a1.y, a1.z, a1.w}};
            float bv[2][4] = {{b0.x, b0.y, b0.z, b0.w}, {b1.x, b1.y, b1.z, b1.w}};
#pragma unroll
            for (int mi = 0; mi < 2; ++mi)
#pragma unroll
                for (int i = 0; i < 4; ++i)
#pragma unroll
                    for (int ni = 0; ni < 2; ++ni)
#pragma unroll
                        for (int j = 0; j < 4; ++j)
                            acc[mi][ni][i][j] = fmaf(av[mi][i], bv[ni][j], acc[mi][ni][i][j]);
        }
        __syncthreads();
    }

#pragma unroll
    for (int mi = 0; mi < 2; ++mi)
#pragma unroll
        for (int i = 0; i < 4; ++i) {
            int gm = m0 + mi * 64 + ty * 4 + i;
            if (gm >= M) continue;
#pragma unroll
            for (int ni = 0; ni < 2; ++ni) {
                int gn = n0 + ni * 64 + tx * 4;
                if (gn >= Nn) continue;
                float* hp = H + (size_t)gm * Nn + gn;
                if (gn + 3 < Nn) {
                    *(float4*)hp = make_float4(acc[mi][ni][i][0], acc[mi][ni][i][1],
                                               acc[mi][ni][i][2], acc[mi][ni][i][3]);
                } else {
#pragma unroll
                    for (int j = 0; j < 4; ++j)
                        if (gn + j < Nn) hp[j] = acc[mi][ni][i][j];
                }
            }
        }
}

// ---------------- pull-gather aggregation (no atomics) ----------------
// OUT[v] = act( bias + dis[v]^2 * H[v] + sum_{s in N(v)} dis[s]*dis[v]*H[s] )
template<bool RELU>
__global__ __launch_bounds__(256)
void k_gather256(const float* __restrict__ H, const int* __restrict__ row_ptr,
                 const int* __restrict__ esrc, const float* __restrict__ dis,
                 const float* __restrict__ bias, float* __restrict__ OUT)
{
    int wid = threadIdx.x >> 6, lane = threadIdx.x & 63;
    int v = blockIdx.x * 4 + wid;
    if (v >= N_NODES) return;
    const float4* H4 = (const float4*)H;
    float dv = dis[v], d2 = dv * dv;
    float4 b = ((const float4*)bias)[lane];
    float4 hv = H4[(size_t)v * 64 + lane];
    float ax = fmaf(hv.x, d2, b.x), ay = fmaf(hv.y, d2, b.y);
    float az = fmaf(hv.z, d2, b.z), aw = fmaf(hv.w, d2, b.w);

    int e = row_ptr[v], e1 = row_ptr[v + 1];
    for (; e + 1 < e1; e += 2) {
        int s0 = esrc[e], s1 = esrc[e + 1];
        float n0 = dis[s0] * dv, n1 = dis[s1] * dv;
        float4 h0 = H4[(size_t)s0 * 64 + lane];
        float4 h1 = H4[(size_t)s1 * 64 + lane];
        ax = fmaf(h0.x, n0, ax); ay = fmaf(h0.y, n0, ay);
        az = fmaf(h0.z, n0, az); aw = fmaf(h0.w, n0, aw);
        ax = fmaf(h1.x, n1, ax); ay = fmaf(h1.y, n1, ay);
        az = fmaf(h1.z, n1, az); aw = fmaf(h1.w, n1, aw);
    }
    if (e < e1) {
        int s = esrc[e];
        float n = dis[s] * dv;
        float4 h = H4[(size_t)s * 64 + lane];
        ax = fmaf(h.x, n, ax); ay = fmaf(h.y, n, ay);
        az = fmaf(h.z, n, az); aw = fmaf(h.w, n, aw);
    }
    if (RELU) {
        ax = fmaxf(ax, 0.f); ay = fmaxf(ay, 0.f);
        az = fmaxf(az, 0.f); aw = fmaxf(aw, 0.f);
    }
    ((float4*)OUT)[(size_t)v * 64 + lane] = make_float4(ax, ay, az, aw);
}

__global__ __launch_bounds__(256)
void k_gather60(const float* __restrict__ H3, const int* __restrict__ row_ptr,
                const int* __restrict__ esrc, const float* __restrict__ dis,
                const float* __restrict__ b3, float* __restrict__ out)
{
    int wid = threadIdx.x >> 6, lane = threadIdx.x & 63;
    int v = blockIdx.x * 4 + wid;
    if (v >= N_NODES || lane >= 60) return;
    float dv = dis[v], d2 = dv * dv;
    float acc = fmaf(H3[(size_t)v * 60 + lane], d2, b3[lane]);
    int e = row_ptr[v], e1 = row_ptr[v + 1];
    for (; e + 1 < e1; e += 2) {
        int s0 = esrc[e], s1 = esrc[e + 1];
        float n0 = dis[s0] * dv, n1 = dis[s1] * dv;
        float h0 = H3[(size_t)s0 * 60 + lane];
        float h1 = H3[(size_t)s1 * 60 + lane];
        acc = fmaf(h0, n0, acc);
        acc = fmaf(h1, n1, acc);
    }
    if (e < e1) {
        int s = esrc[e];
        acc = fmaf(H3[(size_t)s * 60 + lane], dis[s] * dv, acc);
    }
    out[(size_t)v * 60 + lane] = acc;
}

// ---------------- launch ----------------
extern "C" void kernel_launch(void* const* d_in, const int* in_sizes, int n_in,
                              void* d_out, int out_size, void* d_ws, size_t ws_size,
                              hipStream_t stream)
{
    const float* x  = (const float*)d_in[0];
    const int*   ei = (const int*)d_in[1];
    // d_in[2] = batch (identity pooling; unused)
    const float* W1 = (const float*)d_in[3];
    const float* b1 = (const float*)d_in[4];
    const float* W2 = (const float*)d_in[5];
    const float* b2 = (const float*)d_in[6];
    const float* W3 = (const float*)d_in[7];
    const float* b3 = (const float*)d_in[8];
    float* out = (float*)d_out;

    const int* src = ei;
    const int* dst = ei + N_EDGES;

    char* ws = (char*)d_ws;
    int*   cnt      = (int*)(ws + 0);              // 200 KB
    float* dis      = (float*)(ws + 200704);       // 200 KB
    int*   scanned  = (int*)(ws + 401408);         // 200 KB
    int*   blocksum = (int*)(ws + 602112);         // 1 KB
    int*   blockoff = (int*)(ws + 603136);         // 1 KB
    int*   row_ptr  = (int*)(ws + 604160);         // 200 KB (+4)
    int*   cursor   = (int*)(ws + 808960);         // 200 KB
    int*   esrc     = (int*)(ws + 1009664);        // 3.2 MB
    float* bufA     = (float*)(ws + 4210688);      // 51.2 MB
    float* bufB     = (float*)(ws + 55410688);     // 51.2 MB
    float* H3       = (float*)(ws + 106610688);    // 12.0 MB

    // ---- CSR build + normalization ----
    k_cnt_zero<<<SCAN_BLOCKS, 256, 0, stream>>>(cnt);
    k_deg_count<<<(N_EDGES + 255) / 256, 256, 0, stream>>>(dst, cnt);
    k_dis<<<SCAN_BLOCKS, 256, 0, stream>>>(cnt, dis);
    k_scan1<<<SCAN_BLOCKS, 256, 0, stream>>>(cnt, scanned, blocksum);
    k_scan2<<<1, 256, 0, stream>>>(blocksum, blockoff);
    k_scan3<<<SCAN_BLOCKS, 256, 0, stream>>>(scanned, blockoff, row_ptr, cursor);
    k_fill<<<(N_EDGES + 255) / 256, 256, 0, stream>>>(src, dst, cursor, esrc);

    const int MB = (N_NODES + 127) / 128;   // 391
    const int GB = (N_NODES + 3) / 4;       // 12500

    // layer 1
    k_gemm128<<<dim3(2, MB), 256, 0, stream>>>(x, W1, bufA, N_NODES, F_IN, F_HID);
    k_gather256<true><<<GB, 256, 0, stream>>>(bufA, row_ptr, esrc, dis, b1, bufB);
    // layer 2
    k_gemm128<<<dim3(2, MB), 256, 0, stream>>>(bufB, W2, bufA, N_NODES, F_HID, F_HID);
    k_gather256<true><<<GB, 256, 0, stream>>>(bufA, row_ptr, esrc, dis, b2, bufB);
    // layer 3 (pool identity, dropout identity)
    k_gemm128<<<dim3(1, MB), 256, 0, stream>>>(bufB, W3, H3, N_NODES, F_HID, F_OUT);
    k_gather60<<<GB, 256, 0, stream>>>(H3, row_ptr, esrc, dis, b3, out);
}

// Round 6
// 668.802 us; speedup vs baseline: 9.9149x; 1.3000x over previous
//
#include <hip/hip_runtime.h>

#define N_NODES 50000
#define N_EDGES 800000
#define F_IN    512
#define F_HID   256
#define F_OUT   60
#define SCAN_BLOCKS ((N_NODES + 255) / 256)   // 196

typedef __bf16 bf16x8 __attribute__((ext_vector_type(8)));
typedef __bf16 bf16x4 __attribute__((ext_vector_type(4)));
typedef float  f32x4  __attribute__((ext_vector_type(4)));

// Swizzled LDS index (bf16 units) for [row][32] tiles (64 B rows).
// slot = 16B group (8 bf16). XOR with (row>>1)&3: rows 0..7 hit all 8 distinct
// 16B slots mod 128B -> conflict-free ds_read_b128 / ds_write_b128 on both the
// staging side and the fragment-read side (bijective per row).
__device__ __forceinline__ int SWZ(int row, int slot) {
    return row * 32 + (((slot) ^ ((row >> 1) & 3)) << 3);
}

// ---------------- degree / CSR build ----------------
__global__ void k_cnt_zero(int* __restrict__ cnt) {
    int i = blockIdx.x * blockDim.x + threadIdx.x;
    if (i < N_NODES) cnt[i] = 0;
}
__global__ void k_deg_count(const int* __restrict__ dst, int* __restrict__ cnt) {
    int i = blockIdx.x * blockDim.x + threadIdx.x;
    if (i < N_EDGES) atomicAdd(&cnt[dst[i]], 1);
}
__global__ void k_dis(const int* __restrict__ cnt, float* __restrict__ dis) {
    int i = blockIdx.x * blockDim.x + threadIdx.x;
    if (i < N_NODES) dis[i] = rsqrtf((float)(cnt[i] + 1));   // +1 self loop
}
__global__ void k_scan1(const int* __restrict__ cnt, int* __restrict__ scanned,
                        int* __restrict__ blocksum) {
    __shared__ int tmp[256];
    int i = blockIdx.x * 256 + threadIdx.x;
    int v = (i < N_NODES) ? cnt[i] : 0;
    tmp[threadIdx.x] = v;
    __syncthreads();
    for (int off = 1; off < 256; off <<= 1) {
        int t = (threadIdx.x >= off) ? tmp[threadIdx.x - off] : 0;
        __syncthreads();
        tmp[threadIdx.x] += t;
        __syncthreads();
    }
    if (i < N_NODES) scanned[i] = tmp[threadIdx.x] - v;
    if (threadIdx.x == 255) blocksum[blockIdx.x] = tmp[255];
}
__global__ void k_scan2(const int* __restrict__ blocksum, int* __restrict__ blockoff) {
    __shared__ int tmp[256];
    int v = (threadIdx.x < SCAN_BLOCKS) ? blocksum[threadIdx.x] : 0;
    tmp[threadIdx.x] = v;
    __syncthreads();
    for (int off = 1; off < 256; off <<= 1) {
        int t = (threadIdx.x >= off) ? tmp[threadIdx.x - off] : 0;
        __syncthreads();
        tmp[threadIdx.x] += t;
        __syncthreads();
    }
    if (threadIdx.x < SCAN_BLOCKS) blockoff[threadIdx.x] = tmp[threadIdx.x] - v;
}
__global__ void k_scan3(const int* __restrict__ scanned, const int* __restrict__ blockoff,
                        int* __restrict__ row_ptr, int* __restrict__ cursor) {
    int i = blockIdx.x * 256 + threadIdx.x;
    if (i < N_NODES) {
        int rp = scanned[i] + blockoff[blockIdx.x];
        row_ptr[i] = rp;
        cursor[i] = rp;
    }
    if (i == 0) row_ptr[N_NODES] = N_EDGES;
}
__global__ void k_fill(const int* __restrict__ src, const int* __restrict__ dst,
                       int* __restrict__ cursor, int* __restrict__ esrc) {
    int e = blockIdx.x * blockDim.x + threadIdx.x;
    if (e < N_EDGES) {
        int pos = atomicAdd(&cursor[dst[e]], 1);
        esrc[pos] = src[e];
    }
}

// ---------------- W -> W^T split to bf16 hi/lo ----------------
// W is [K][N] fp32; output Wt_{h,l} is [NP][K] bf16 (rows n>=N zeroed).
__global__ void k_cvt_wT(const float* __restrict__ W, __bf16* __restrict__ th,
                         __bf16* __restrict__ tl, int K, int N, int NP) {
    int i = blockIdx.x * 256 + threadIdx.x;
    if (i >= NP * K) return;
    int n = i / K, k = i - n * K;
    float w = (n < N) ? W[(size_t)k * N + n] : 0.f;
    __bf16 h = (__bf16)w;
    th[i] = h;
    tl[i] = (__bf16)(w - (float)h);
}

// ---------------- MFMA GEMM: H(MxN) = A(MxK) @ Bt(NxK)^T, split-bf16 ----------------
// Tile 128x64, BK=32, 4 waves (2M x 2N), each wave 64x32 (4x2 16x16 frags).
// A_FP32: A is fp32, converted to hi/lo during staging. Else A pre-split (Ahi/Alo).
template<bool A_FP32>
__global__ __launch_bounds__(256)
void k_gemm_mfma(const float* __restrict__ Af,
                 const __bf16* __restrict__ Ahi, const __bf16* __restrict__ Alo,
                 const __bf16* __restrict__ Bth, const __bf16* __restrict__ Btl,
                 float* __restrict__ H, int M, int N, int K)
{
    __shared__ __bf16 smem[12288];          // 24 KB
    __bf16* sAh = smem;                     // [128][32]
    __bf16* sAl = smem + 4096;
    __bf16* sBh = smem + 8192;              // [64][32]
    __bf16* sBl = smem + 10240;

    const int tid = threadIdx.x;
    const int m0 = blockIdx.y * 128;
    const int n0 = blockIdx.x * 64;
    const int lane = tid & 63, wid = tid >> 6;
    const int wm = wid >> 1, wn = wid & 1;

    f32x4 acc[4][2];
#pragma unroll
    for (int f = 0; f < 4; ++f)
#pragma unroll
        for (int g = 0; g < 2; ++g)
            acc[f][g] = (f32x4){0.f, 0.f, 0.f, 0.f};

    for (int k0 = 0; k0 < K; k0 += 32) {
        // ---- stage A ----
        if (A_FP32) {
            int row = tid >> 1, c0 = (tid & 1) * 16;
            int gm = m0 + row;
            float av[16];
            if (gm < M) {
                const float* p = Af + (size_t)gm * K + k0 + c0;
                *(float4*)&av[0]  = *(const float4*)(p + 0);
                *(float4*)&av[4]  = *(const float4*)(p + 4);
                *(float4*)&av[8]  = *(const float4*)(p + 8);
                *(float4*)&av[12] = *(const float4*)(p + 12);
            } else {
#pragma unroll
                for (int j = 0; j < 16; ++j) av[j] = 0.f;
            }
            bf16x8 h0, h1, l0, l1;
#pragma unroll
            for (int j = 0; j < 8; ++j) {
                __bf16 h = (__bf16)av[j];
                h0[j] = h; l0[j] = (__bf16)(av[j] - (float)h);
                __bf16 h2 = (__bf16)av[8 + j];
                h1[j] = h2; l1[j] = (__bf16)(av[8 + j] - (float)h2);
            }
            int s0 = (tid & 1) * 2;
            *(bf16x8*)&sAh[SWZ(row, s0)]     = h0;
            *(bf16x8*)&sAh[SWZ(row, s0 + 1)] = h1;
            *(bf16x8*)&sAl[SWZ(row, s0)]     = l0;
            *(bf16x8*)&sAl[SWZ(row, s0 + 1)] = l1;
        } else {
#pragma unroll
            for (int it = 0; it < 2; ++it) {
                int c = tid + it * 256;
                int row = c >> 2, slot = c & 3;
                int gm = m0 + row;
                bf16x8 vh = {}, vl = {};
                if (gm < M) {
                    vh = *(const bf16x8*)(Ahi + (size_t)gm * K + k0 + slot * 8);
                    vl = *(const bf16x8*)(Alo + (size_t)gm * K + k0 + slot * 8);
                }
                *(bf16x8*)&sAh[SWZ(row, slot)] = vh;
                *(bf16x8*)&sAl[SWZ(row, slot)] = vl;
            }
        }
        // ---- stage B (Bt rows always in-bounds: padded) ----
        {
            int row = tid >> 2, slot = tid & 3;
            size_t off = (size_t)(n0 + row) * K + k0 + slot * 8;
            *(bf16x8*)&sBh[SWZ(row, slot)] = *(const bf16x8*)(Bth + off);
            *(bf16x8*)&sBl[SWZ(row, slot)] = *(const bf16x8*)(Btl + off);
        }
        __syncthreads();

        bf16x8 ah[4], al[4], bh[2], bl[2];
#pragma unroll
        for (int f = 0; f < 4; ++f) {
            int r = wm * 64 + f * 16 + (lane & 15);
            ah[f] = *(const bf16x8*)&sAh[SWZ(r, lane >> 4)];
            al[f] = *(const bf16x8*)&sAl[SWZ(r, lane >> 4)];
        }
#pragma unroll
        for (int g = 0; g < 2; ++g) {
            int r = wn * 32 + g * 16 + (lane & 15);
            bh[g] = *(const bf16x8*)&sBh[SWZ(r, lane >> 4)];
            bl[g] = *(const bf16x8*)&sBl[SWZ(r, lane >> 4)];
        }
#pragma unroll
        for (int f = 0; f < 4; ++f)
#pragma unroll
            for (int g = 0; g < 2; ++g) {
                acc[f][g] = __builtin_amdgcn_mfma_f32_16x16x32_bf16(ah[f], bh[g], acc[f][g], 0, 0, 0);
                acc[f][g] = __builtin_amdgcn_mfma_f32_16x16x32_bf16(al[f], bh[g], acc[f][g], 0, 0, 0);
                acc[f][g] = __builtin_amdgcn_mfma_f32_16x16x32_bf16(ah[f], bl[g], acc[f][g], 0, 0, 0);
            }
        __syncthreads();
    }

    // epilogue: D[row][col], col = lane&15, row = (lane>>4)*4 + r
#pragma unroll
    for (int f = 0; f < 4; ++f)
#pragma unroll
        for (int g = 0; g < 2; ++g) {
            int col = n0 + wn * 32 + g * 16 + (lane & 15);
            if (col >= N) continue;
#pragma unroll
            for (int r = 0; r < 4; ++r) {
                int row = m0 + wm * 64 + f * 16 + (lane >> 4) * 4 + r;
                if (row < M) H[(size_t)row * N + col] = acc[f][g][r];
            }
        }
}

// ---------------- pull-gather aggregation (no atomics), bf16 hi/lo output ----------------
// OUT[v] = relu( bias + dis[v]^2 * H[v] + sum_{s in N(v)} dis[s]*dis[v]*H[s] )
__global__ __launch_bounds__(256)
void k_gather256(const float* __restrict__ H, const int* __restrict__ row_ptr,
                 const int* __restrict__ esrc, const float* __restrict__ dis,
                 const float* __restrict__ bias,
                 __bf16* __restrict__ Ghi, __bf16* __restrict__ Glo)
{
    int wid = threadIdx.x >> 6, lane = threadIdx.x & 63;
    int v = blockIdx.x * 4 + wid;
    if (v >= N_NODES) return;
    const float4* H4 = (const float4*)H;
    float dv = dis[v], d2 = dv * dv;
    float4 b = ((const float4*)bias)[lane];
    float4 hv = H4[(size_t)v * 64 + lane];
    float ax = fmaf(hv.x, d2, b.x), ay = fmaf(hv.y, d2, b.y);
    float az = fmaf(hv.z, d2, b.z), aw = fmaf(hv.w, d2, b.w);

    int e = row_ptr[v], e1 = row_ptr[v + 1];
    for (; e + 1 < e1; e += 2) {
        int s0 = esrc[e], s1 = esrc[e + 1];
        float n0 = dis[s0] * dv, n1 = dis[s1] * dv;
        float4 h0 = H4[(size_t)s0 * 64 + lane];
        float4 h1 = H4[(size_t)s1 * 64 + lane];
        ax = fmaf(h0.x, n0, ax); ay = fmaf(h0.y, n0, ay);
        az = fmaf(h0.z, n0, az); aw = fmaf(h0.w, n0, aw);
        ax = fmaf(h1.x, n1, ax); ay = fmaf(h1.y, n1, ay);
        az = fmaf(h1.z, n1, az); aw = fmaf(h1.w, n1, aw);
    }
    if (e < e1) {
        int s = esrc[e];
        float n = dis[s] * dv;
        float4 h = H4[(size_t)s * 64 + lane];
        ax = fmaf(h.x, n, ax); ay = fmaf(h.y, n, ay);
        az = fmaf(h.z, n, az); aw = fmaf(h.w, n, aw);
    }
    ax = fmaxf(ax, 0.f); ay = fmaxf(ay, 0.f);
    az = fmaxf(az, 0.f); aw = fmaxf(aw, 0.f);

    bf16x4 h, l;
    h[0] = (__bf16)ax; l[0] = (__bf16)(ax - (float)h[0]);
    h[1] = (__bf16)ay; l[1] = (__bf16)(ay - (float)h[1]);
    h[2] = (__bf16)az; l[2] = (__bf16)(az - (float)h[2]);
    h[3] = (__bf16)aw; l[3] = (__bf16)(aw - (float)h[3]);
    size_t o = (size_t)v * 256 + lane * 4;
    *(bf16x4*)&Ghi[o] = h;
    *(bf16x4*)&Glo[o] = l;
}

__global__ __launch_bounds__(256)
void k_gather60(const float* __restrict__ H3, const int* __restrict__ row_ptr,
                const int* __restrict__ esrc, const float* __restrict__ dis,
                const float* __restrict__ b3, float* __restrict__ out)
{
    int wid = threadIdx.x >> 6, lane = threadIdx.x & 63;
    int v = blockIdx.x * 4 + wid;
    if (v >= N_NODES || lane >= 60) return;
    float dv = dis[v], d2 = dv * dv;
    float acc = fmaf(H3[(size_t)v * 60 + lane], d2, b3[lane]);
    int e = row_ptr[v], e1 = row_ptr[v + 1];
    for (; e + 1 < e1; e += 2) {
        int s0 = esrc[e], s1 = esrc[e + 1];
        float n0 = dis[s0] * dv, n1 = dis[s1] * dv;
        float h0 = H3[(size_t)s0 * 60 + lane];
        float h1 = H3[(size_t)s1 * 60 + lane];
        acc = fmaf(h0, n0, acc);
        acc = fmaf(h1, n1, acc);
    }
    if (e < e1) {
        int s = esrc[e];
        acc = fmaf(H3[(size_t)s * 60 + lane], dis[s] * dv, acc);
    }
    out[(size_t)v * 60 + lane] = acc;
}

// ---------------- launch ----------------
extern "C" void kernel_launch(void* const* d_in, const int* in_sizes, int n_in,
                              void* d_out, int out_size, void* d_ws, size_t ws_size,
                              hipStream_t stream)
{
    const float* x  = (const float*)d_in[0];
    const int*   ei = (const int*)d_in[1];
    const float* W1 = (const float*)d_in[3];
    const float* b1 = (const float*)d_in[4];
    const float* W2 = (const float*)d_in[5];
    const float* b2 = (const float*)d_in[6];
    const float* W3 = (const float*)d_in[7];
    const float* b3 = (const float*)d_in[8];
    float* out = (float*)d_out;

    const int* src = ei;
    const int* dst = ei + N_EDGES;

    char* ws = (char*)d_ws;
    int*    cnt      = (int*)(ws + 0);
    float*  dis      = (float*)(ws + 200704);
    int*    scanned  = (int*)(ws + 401408);
    int*    blocksum = (int*)(ws + 602112);
    int*    blockoff = (int*)(ws + 603136);
    int*    row_ptr  = (int*)(ws + 604160);
    int*    cursor   = (int*)(ws + 805376);
    int*    esrc     = (int*)(ws + 1006080);
    __bf16* w1h      = (__bf16*)(ws + 4206592);
    __bf16* w1l      = (__bf16*)(ws + 4468736);
    __bf16* w2h      = (__bf16*)(ws + 4730880);
    __bf16* w2l      = (__bf16*)(ws + 4861952);
    __bf16* w3h      = (__bf16*)(ws + 4993024);
    __bf16* w3l      = (__bf16*)(ws + 5025792);
    float*  H        = (float*)(ws + 5058560);     // 51.2 MB
    __bf16* Ghi      = (__bf16*)(ws + 56258560);   // 25.6 MB
    __bf16* Glo      = (__bf16*)(ws + 81858560);   // 25.6 MB

    // ---- CSR build + normalization ----
    k_cnt_zero<<<SCAN_BLOCKS, 256, 0, stream>>>(cnt);
    k_deg_count<<<(N_EDGES + 255) / 256, 256, 0, stream>>>(dst, cnt);
    k_dis<<<SCAN_BLOCKS, 256, 0, stream>>>(cnt, dis);
    k_scan1<<<SCAN_BLOCKS, 256, 0, stream>>>(cnt, scanned, blocksum);
    k_scan2<<<1, 256, 0, stream>>>(blocksum, blockoff);
    k_scan3<<<SCAN_BLOCKS, 256, 0, stream>>>(scanned, blockoff, row_ptr, cursor);
    k_fill<<<(N_EDGES + 255) / 256, 256, 0, stream>>>(src, dst, cursor, esrc);

    // ---- weight transpose + split ----
    k_cvt_wT<<<(256 * 512 + 255) / 256, 256, 0, stream>>>(W1, w1h, w1l, 512, 256, 256);
    k_cvt_wT<<<(256 * 256 + 255) / 256, 256, 0, stream>>>(W2, w2h, w2l, 256, 256, 256);
    k_cvt_wT<<<(64 * 256 + 255) / 256, 256, 0, stream>>>(W3, w3h, w3l, 256, 60, 64);

    const int MB = (N_NODES + 127) / 128;   // 391
    const int GB = (N_NODES + 3) / 4;       // 12500

    // layer 1
    k_gemm_mfma<true><<<dim3(4, MB), 256, 0, stream>>>(x, nullptr, nullptr, w1h, w1l,
                                                       H, N_NODES, F_HID, F_IN);
    k_gather256<<<GB, 256, 0, stream>>>(H, row_ptr, esrc, dis, b1, Ghi, Glo);
    // layer 2
    k_gemm_mfma<false><<<dim3(4, MB), 256, 0, stream>>>(nullptr, Ghi, Glo, w2h, w2l,
                                                        H, N_NODES, F_HID, F_HID);
    k_gather256<<<GB, 256, 0, stream>>>(H, row_ptr, esrc, dis, b2, Ghi, Glo);
    // layer 3 (pool identity, dropout identity)
    k_gemm_mfma<false><<<dim3(1, MB), 256, 0, stream>>>(nullptr, Ghi, Glo, w3h, w3l,
                                                        H, N_NODES, F_OUT, F_HID);
    k_gather60<<<GB, 256, 0, stream>>>(H, row_ptr, esrc, dis, b3, out);
}

// Round 8
// 511.672 us; speedup vs baseline: 12.9597x; 1.3071x over previous
//
#include <hip/hip_runtime.h>

#define N_NODES 50000
#define N_EDGES 800000
#define F_IN    512
#define F_HID   256
#define F_OUT   60
#define SCAN_BLOCKS ((N_NODES + 255) / 256)   // 196

typedef __bf16    bf16x8 __attribute__((ext_vector_type(8)));
typedef __bf16    bf16x4 __attribute__((ext_vector_type(4)));
typedef float     f32x4  __attribute__((ext_vector_type(4)));
typedef _Float16  f16x4  __attribute__((ext_vector_type(4)));
typedef _Float16  f16x2  __attribute__((ext_vector_type(2)));

// Swizzled LDS index (bf16 units) for [row][32] tiles (64 B rows).
// slot = 16B group (8 bf16). XOR with (row>>1)&3: conflict-free ds_read_b128 /
// ds_write_b128 on both staging and fragment-read sides (bijective per row).
__device__ __forceinline__ int SWZ(int row, int slot) {
    return row * 32 + (((slot) ^ ((row >> 1) & 3)) << 3);
}

// ---------------- degree / CSR build ----------------
__global__ void k_cnt_zero(int* __restrict__ cnt) {
    int i = blockIdx.x * blockDim.x + threadIdx.x;
    if (i < N_NODES) cnt[i] = 0;
}
__global__ void k_deg_count(const int* __restrict__ dst, int* __restrict__ cnt) {
    int i = blockIdx.x * blockDim.x + threadIdx.x;
    if (i < N_EDGES) atomicAdd(&cnt[dst[i]], 1);
}
__global__ void k_dis(const int* __restrict__ cnt, float* __restrict__ dis) {
    int i = blockIdx.x * blockDim.x + threadIdx.x;
    if (i < N_NODES) dis[i] = rsqrtf((float)(cnt[i] + 1));   // +1 self loop
}
__global__ void k_scan1(const int* __restrict__ cnt, int* __restrict__ scanned,
                        int* __restrict__ blocksum) {
    __shared__ int tmp[256];
    int i = blockIdx.x * 256 + threadIdx.x;
    int v = (i < N_NODES) ? cnt[i] : 0;
    tmp[threadIdx.x] = v;
    __syncthreads();
    for (int off = 1; off < 256; off <<= 1) {
        int t = (threadIdx.x >= off) ? tmp[threadIdx.x - off] : 0;
        __syncthreads();
        tmp[threadIdx.x] += t;
        __syncthreads();
    }
    if (i < N_NODES) scanned[i] = tmp[threadIdx.x] - v;
    if (threadIdx.x == 255) blocksum[blockIdx.x] = tmp[255];
}
__global__ void k_scan2(const int* __restrict__ blocksum, int* __restrict__ blockoff) {
    __shared__ int tmp[256];
    int v = (threadIdx.x < SCAN_BLOCKS) ? blocksum[threadIdx.x] : 0;
    tmp[threadIdx.x] = v;
    __syncthreads();
    for (int off = 1; off < 256; off <<= 1) {
        int t = (threadIdx.x >= off) ? tmp[threadIdx.x - off] : 0;
        __syncthreads();
        tmp[threadIdx.x] += t;
        __syncthreads();
    }
    if (threadIdx.x < SCAN_BLOCKS) blockoff[threadIdx.x] = tmp[threadIdx.x] - v;
}
__global__ void k_scan3(const int* __restrict__ scanned, const int* __restrict__ blockoff,
                        int* __restrict__ row_ptr, int* __restrict__ cursor) {
    int i = blockIdx.x * 256 + threadIdx.x;
    if (i < N_NODES) {
        int rp = scanned[i] + blockoff[blockIdx.x];
        row_ptr[i] = rp;
        cursor[i] = rp;
    }
    if (i == 0) row_ptr[N_NODES] = N_EDGES;
}
__global__ void k_fill(const int* __restrict__ src, const int* __restrict__ dst,
                       int* __restrict__ cursor, int* __restrict__ esrc) {
    int e = blockIdx.x * blockDim.x + threadIdx.x;
    if (e < N_EDGES) {
        int pos = atomicAdd(&cursor[dst[e]], 1);
        esrc[pos] = src[e];
    }
}

// ---------------- W -> W^T split to bf16 hi/lo ----------------
__global__ void k_cvt_wT(const float* __restrict__ W, __bf16* __restrict__ th,
                         __bf16* __restrict__ tl, int K, int N, int NP) {
    int i = blockIdx.x * 256 + threadIdx.x;
    if (i >= NP * K) return;
    int n = i / K, k = i - n * K;
    float w = (n < N) ? W[(size_t)k * N + n] : 0.f;
    __bf16 h = (__bf16)w;
    th[i] = h;
    tl[i] = (__bf16)(w - (float)h);
}

// ---------------- wide MFMA GEMM: H(Mx256) = A(MxK) @ Bt(256xK)^T ----------------
// Tile 128x256 (all of N), BK=32, 512 threads = 8 waves (2M x 4N), 64x64/wave.
// A read exactly once from HBM. Output fp16.
template<bool A_FP32>
__global__ __launch_bounds__(512)
void k_gemm_n256(const float* __restrict__ Af,
                 const __bf16* __restrict__ Ahi, const __bf16* __restrict__ Alo,
                 const __bf16* __restrict__ Bth, const __bf16* __restrict__ Btl,
                 _Float16* __restrict__ H, int M, int K)
{
    __shared__ __bf16 smem[24576];          // 48 KB
    __bf16* sAh = smem;                     // [128][32]
    __bf16* sAl = smem + 4096;
    __bf16* sBh = smem + 8192;              // [256][32]
    __bf16* sBl = smem + 16384;

    const int tid = threadIdx.x;
    const int m0 = blockIdx.y * 128;
    const int lane = tid & 63, wid = tid >> 6;
    const int wm = wid >> 2, wn = wid & 3;

    f32x4 acc[4][4];
#pragma unroll
    for (int f = 0; f < 4; ++f)
#pragma unroll
        for (int g = 0; g < 4; ++g)
            acc[f][g] = (f32x4){0.f, 0.f, 0.f, 0.f};

    for (int k0 = 0; k0 < K; k0 += 32) {
        // ---- stage A: 128 rows x 4 slots, one slot per thread ----
        {
            int row = tid >> 2, slot = tid & 3;
            int gm = m0 + row;
            if (A_FP32) {
                float av[8];
                if (gm < M) {
                    const float* p = Af + (size_t)gm * K + k0 + slot * 8;
                    *(float4*)&av[0] = *(const float4*)(p);
                    *(float4*)&av[4] = *(const float4*)(p + 4);
                } else {
#pragma unroll
                    for (int j = 0; j < 8; ++j) av[j] = 0.f;
                }
                bf16x8 h, l;
#pragma unroll
                for (int j = 0; j < 8; ++j) {
                    __bf16 hh = (__bf16)av[j];
                    h[j] = hh; l[j] = (__bf16)(av[j] - (float)hh);
                }
                *(bf16x8*)&sAh[SWZ(row, slot)] = h;
                *(bf16x8*)&sAl[SWZ(row, slot)] = l;
            } else {
                bf16x8 vh = {}, vl = {};
                if (gm < M) {
                    vh = *(const bf16x8*)(Ahi + (size_t)gm * K + k0 + slot * 8);
                    vl = *(const bf16x8*)(Alo + (size_t)gm * K + k0 + slot * 8);
                }
                *(bf16x8*)&sAh[SWZ(row, slot)] = vh;
                *(bf16x8*)&sAl[SWZ(row, slot)] = vl;
            }
        }
        // ---- stage B: 256 rows x 4 slots, two slots per thread ----
        {
            int row = tid >> 1, s0 = (tid & 1) * 2;
            size_t off = (size_t)row * K + k0 + s0 * 8;
            *(bf16x8*)&sBh[SWZ(row, s0)]     = *(const bf16x8*)(Bth + off);
            *(bf16x8*)&sBh[SWZ(row, s0 + 1)] = *(const bf16x8*)(Bth + off + 8);
            *(bf16x8*)&sBl[SWZ(row, s0)]     = *(const bf16x8*)(Btl + off);
            *(bf16x8*)&sBl[SWZ(row, s0 + 1)] = *(const bf16x8*)(Btl + off + 8);
        }
        __syncthreads();

        bf16x8 ah[4], al[4], bh[4], bl[4];
#pragma unroll
        for (int f = 0; f < 4; ++f) {
            int r = wm * 64 + f * 16 + (lane & 15);
            ah[f] = *(const bf16x8*)&sAh[SWZ(r, lane >> 4)];
            al[f] = *(const bf16x8*)&sAl[SWZ(r, lane >> 4)];
        }
#pragma unroll
        for (int g = 0; g < 4; ++g) {
            int r = wn * 64 + g * 16 + (lane & 15);
            bh[g] = *(const bf16x8*)&sBh[SWZ(r, lane >> 4)];
            bl[g] = *(const bf16x8*)&sBl[SWZ(r, lane >> 4)];
        }
#pragma unroll
        for (int f = 0; f < 4; ++f)
#pragma unroll
            for (int g = 0; g < 4; ++g) {
                acc[f][g] = __builtin_amdgcn_mfma_f32_16x16x32_bf16(ah[f], bh[g], acc[f][g], 0, 0, 0);
                acc[f][g] = __builtin_amdgcn_mfma_f32_16x16x32_bf16(al[f], bh[g], acc[f][g], 0, 0, 0);
                acc[f][g] = __builtin_amdgcn_mfma_f32_16x16x32_bf16(ah[f], bl[g], acc[f][g], 0, 0, 0);
            }
        __syncthreads();
    }

    // epilogue (fp16 out): col = lane&15 base, row = (lane>>4)*4 + r
#pragma unroll
    for (int f = 0; f < 4; ++f)
#pragma unroll
        for (int g = 0; g < 4; ++g) {
            int col = wn * 64 + g * 16 + (lane & 15);
#pragma unroll
            for (int r = 0; r < 4; ++r) {
                int row = m0 + wm * 64 + f * 16 + (lane >> 4) * 4 + r;
                if (row < M) H[(size_t)row * 256 + col] = (_Float16)acc[f][g][r];
            }
        }
}

// ---------------- narrow MFMA GEMM (layer 3): H(MxN) = A(MxK) @ Bt ----------------
// Tile 128x64, BK=32, 4 waves (2M x 2N). Output fp16, row stride N (=60).
__global__ __launch_bounds__(256)
void k_gemm_n64(const __bf16* __restrict__ Ahi, const __bf16* __restrict__ Alo,
                const __bf16* __restrict__ Bth, const __bf16* __restrict__ Btl,
                _Float16* __restrict__ H, int M, int N, int K)
{
    __shared__ __bf16 smem[12288];          // 24 KB
    __bf16* sAh = smem;                     // [128][32]
    __bf16* sAl = smem + 4096;
    __bf16* sBh = smem + 8192;              // [64][32]
    __bf16* sBl = smem + 10240;

    const int tid = threadIdx.x;
    const int m0 = blockIdx.y * 128;
    const int lane = tid & 63, wid = tid >> 6;
    const int wm = wid >> 1, wn = wid & 1;

    f32x4 acc[4][2];
#pragma unroll
    for (int f = 0; f < 4; ++f)
#pragma unroll
        for (int g = 0; g < 2; ++g)
            acc[f][g] = (f32x4){0.f, 0.f, 0.f, 0.f};

    for (int k0 = 0; k0 < K; k0 += 32) {
#pragma unroll
        for (int it = 0; it < 2; ++it) {
            int c = tid + it * 256;
            int row = c >> 2, slot = c & 3;
            int gm = m0 + row;
            bf16x8 vh = {}, vl = {};
            if (gm < M) {
                vh = *(const bf16x8*)(Ahi + (size_t)gm * K + k0 + slot * 8);
                vl = *(const bf16x8*)(Alo + (size_t)gm * K + k0 + slot * 8);
            }
            *(bf16x8*)&sAh[SWZ(row, slot)] = vh;
            *(bf16x8*)&sAl[SWZ(row, slot)] = vl;
        }
        {
            int row = tid >> 2, slot = tid & 3;
            size_t off = (size_t)row * K + k0 + slot * 8;
            *(bf16x8*)&sBh[SWZ(row, slot)] = *(const bf16x8*)(Bth + off);
            *(bf16x8*)&sBl[SWZ(row, slot)] = *(const bf16x8*)(Btl + off);
        }
        __syncthreads();

        bf16x8 ah[4], al[4], bh[2], bl[2];
#pragma unroll
        for (int f = 0; f < 4; ++f) {
            int r = wm * 64 + f * 16 + (lane & 15);
            ah[f] = *(const bf16x8*)&sAh[SWZ(r, lane >> 4)];
            al[f] = *(const bf16x8*)&sAl[SWZ(r, lane >> 4)];
        }
#pragma unroll
        for (int g = 0; g < 2; ++g) {
            int r = wn * 32 + g * 16 + (lane & 15);
            bh[g] = *(const bf16x8*)&sBh[SWZ(r, lane >> 4)];
            bl[g] = *(const bf16x8*)&sBl[SWZ(r, lane >> 4)];
        }
#pragma unroll
        for (int f = 0; f < 4; ++f)
#pragma unroll
            for (int g = 0; g < 2; ++g) {
                acc[f][g] = __builtin_amdgcn_mfma_f32_16x16x32_bf16(ah[f], bh[g], acc[f][g], 0, 0, 0);
                acc[f][g] = __builtin_amdgcn_mfma_f32_16x16x32_bf16(al[f], bh[g], acc[f][g], 0, 0, 0);
                acc[f][g] = __builtin_amdgcn_mfma_f32_16x16x32_bf16(ah[f], bl[g], acc[f][g], 0, 0, 0);
            }
        __syncthreads();
    }

#pragma unroll
    for (int f = 0; f < 4; ++f)
#pragma unroll
        for (int g = 0; g < 2; ++g) {
            int col = wn * 32 + g * 16 + (lane & 15);
            if (col >= N) continue;
#pragma unroll
            for (int r = 0; r < 4; ++r) {
                int row = m0 + wm * 64 + f * 16 + (lane >> 4) * 4 + r;
                if (row < M) H[(size_t)row * N + col] = (_Float16)acc[f][g][r];
            }
        }
}

// ---------------- pull-gather (fp16 in, bf16 hi/lo out), 4x unrolled ----------------
__global__ __launch_bounds__(256)
void k_gather256(const _Float16* __restrict__ H, const int* __restrict__ row_ptr,
                 const int* __restrict__ esrc, const float* __restrict__ dis,
                 const float* __restrict__ bias,
                 __bf16* __restrict__ Ghi, __bf16* __restrict__ Glo)
{
    int wid = threadIdx.x >> 6, lane = threadIdx.x & 63;
    int v = blockIdx.x * 4 + wid;
    if (v >= N_NODES) return;
    const f16x4* H4 = (const f16x4*)H;
    float dv = dis[v], d2 = dv * dv;
    float4 b = ((const float4*)bias)[lane];
    f16x4 hv = H4[(size_t)v * 64 + lane];
    float a0 = fmaf((float)hv[0], d2, b.x);
    float a1 = fmaf((float)hv[1], d2, b.y);
    float a2 = fmaf((float)hv[2], d2, b.z);
    float a3 = fmaf((float)hv[3], d2, b.w);

    int e = row_ptr[v], e1 = row_ptr[v + 1];
    for (; e + 3 < e1; e += 4) {
        int s0 = esrc[e], s1 = esrc[e + 1], s2 = esrc[e + 2], s3 = esrc[e + 3];
        float n0 = dis[s0] * dv, n1 = dis[s1] * dv;
        float n2 = dis[s2] * dv, n3 = dis[s3] * dv;
        f16x4 h0 = H4[(size_t)s0 * 64 + lane];
        f16x4 h1 = H4[(size_t)s1 * 64 + lane];
        f16x4 h2 = H4[(size_t)s2 * 64 + lane];
        f16x4 h3 = H4[(size_t)s3 * 64 + lane];
        a0 = fmaf((float)h0[0], n0, a0); a1 = fmaf((float)h0[1], n0, a1);
        a2 = fmaf((float)h0[2], n0, a2); a3 = fmaf((float)h0[3], n0, a3);
        a0 = fmaf((float)h1[0], n1, a0); a1 = fmaf((float)h1[1], n1, a1);
        a2 = fmaf((float)h1[2], n1, a2); a3 = fmaf((float)h1[3], n1, a3);
        a0 = fmaf((float)h2[0], n2, a0); a1 = fmaf((float)h2[1], n2, a1);
        a2 = fmaf((float)h2[2], n2, a2); a3 = fmaf((float)h2[3], n2, a3);
        a0 = fmaf((float)h3[0], n3, a0); a1 = fmaf((float)h3[1], n3, a1);
        a2 = fmaf((float)h3[2], n3, a2); a3 = fmaf((float)h3[3], n3, a3);
    }
    for (; e < e1; ++e) {
        int s = esrc[e];
        float n = dis[s] * dv;
        f16x4 h = H4[(size_t)s * 64 + lane];
        a0 = fmaf((float)h[0], n, a0); a1 = fmaf((float)h[1], n, a1);
        a2 = fmaf((float)h[2], n, a2); a3 = fmaf((float)h[3], n, a3);
    }
    a0 = fmaxf(a0, 0.f); a1 = fmaxf(a1, 0.f);
    a2 = fmaxf(a2, 0.f); a3 = fmaxf(a3, 0.f);

    bf16x4 h, l;
    h[0] = (__bf16)a0; l[0] = (__bf16)(a0 - (float)h[0]);
    h[1] = (__bf16)a1; l[1] = (__bf16)(a1 - (float)h[1]);
    h[2] = (__bf16)a2; l[2] = (__bf16)(a2 - (float)h[2]);
    h[3] = (__bf16)a3; l[3] = (__bf16)(a3 - (float)h[3]);
    size_t o = (size_t)v * 256 + lane * 4;
    *(bf16x4*)&Ghi[o] = h;
    *(bf16x4*)&Glo[o] = l;
}

__global__ __launch_bounds__(256)
void k_gather60(const _Float16* __restrict__ H3, const int* __restrict__ row_ptr,
                const int* __restrict__ esrc, const float* __restrict__ dis,
                const float* __restrict__ b3, float* __restrict__ out)
{
    int wid = threadIdx.x >> 6, lane = threadIdx.x & 63;
    int v = blockIdx.x * 4 + wid;
    if (v >= N_NODES || lane >= 30) return;
    const f16x2* H2 = (const f16x2*)H3;
    float dv = dis[v], d2 = dv * dv;
    f16x2 hv = H2[(size_t)v * 30 + lane];
    float a0 = fmaf((float)hv[0], d2, b3[lane * 2]);
    float a1 = fmaf((float)hv[1], d2, b3[lane * 2 + 1]);
    int e = row_ptr[v], e1 = row_ptr[v + 1];
    for (; e + 1 < e1; e += 2) {
        int s0 = esrc[e], s1 = esrc[e + 1];
        float n0 = dis[s0] * dv, n1 = dis[s1] * dv;
        f16x2 h0 = H2[(size_t)s0 * 30 + lane];
        f16x2 h1 = H2[(size_t)s1 * 30 + lane];
        a0 = fmaf((float)h0[0], n0, a0); a1 = fmaf((float)h0[1], n0, a1);
        a0 = fmaf((float)h1[0], n1, a0); a1 = fmaf((float)h1[1], n1, a1);
    }
    if (e < e1) {
        int s = esrc[e];
        float n = dis[s] * dv;
        f16x2 h = H2[(size_t)s * 30 + lane];
        a0 = fmaf((float)h[0], n, a0); a1 = fmaf((float)h[1], n, a1);
    }
    out[(size_t)v * 60 + lane * 2]     = a0;
    out[(size_t)v * 60 + lane * 2 + 1] = a1;
}

// ---------------- launch ----------------
extern "C" void kernel_launch(void* const* d_in, const int* in_sizes, int n_in,
                              void* d_out, int out_size, void* d_ws, size_t ws_size,
                              hipStream_t stream)
{
    const float* x  = (const float*)d_in[0];
    const int*   ei = (const int*)d_in[1];
    const float* W1 = (const float*)d_in[3];
    const float* b1 = (const float*)d_in[4];
    const float* W2 = (const float*)d_in[5];
    const float* b2 = (const float*)d_in[6];
    const float* W3 = (const float*)d_in[7];
    const float* b3 = (const float*)d_in[8];
    float* out = (float*)d_out;

    const int* src = ei;
    const int* dst = ei + N_EDGES;

    char* ws = (char*)d_ws;
    int*      cnt      = (int*)(ws + 0);
    float*    dis      = (float*)(ws + 200704);
    int*      scanned  = (int*)(ws + 401408);
    int*      blocksum = (int*)(ws + 602112);
    int*      blockoff = (int*)(ws + 603136);
    int*      row_ptr  = (int*)(ws + 604160);
    int*      cursor   = (int*)(ws + 805376);
    int*      esrc     = (int*)(ws + 1006080);
    __bf16*   w1h      = (__bf16*)(ws + 4206592);
    __bf16*   w1l      = (__bf16*)(ws + 4468736);
    __bf16*   w2h      = (__bf16*)(ws + 4730880);
    __bf16*   w2l      = (__bf16*)(ws + 4861952);
    __bf16*   w3h      = (__bf16*)(ws + 4993024);
    __bf16*   w3l      = (__bf16*)(ws + 5025792);
    _Float16* H        = (_Float16*)(ws + 5058560);    // 25.6 MB
    __bf16*   Ghi      = (__bf16*)(ws + 30658560);     // 25.6 MB
    __bf16*   Glo      = (__bf16*)(ws + 56258560);     // 25.6 MB
    _Float16* H3       = (_Float16*)(ws + 81858560);   // 6.0 MB

    // ---- CSR build + normalization ----
    k_cnt_zero<<<SCAN_BLOCKS, 256, 0, stream>>>(cnt);
    k_deg_count<<<(N_EDGES + 255) / 256, 256, 0, stream>>>(dst, cnt);
    k_dis<<<SCAN_BLOCKS, 256, 0, stream>>>(cnt, dis);
    k_scan1<<<SCAN_BLOCKS, 256, 0, stream>>>(cnt, scanned, blocksum);
    k_scan2<<<1, 256, 0, stream>>>(blocksum, blockoff);
    k_scan3<<<SCAN_BLOCKS, 256, 0, stream>>>(scanned, blockoff, row_ptr, cursor);
    k_fill<<<(N_EDGES + 255) / 256, 256, 0, stream>>>(src, dst, cursor, esrc);

    // ---- weight transpose + split ----
    k_cvt_wT<<<(256 * 512 + 255) / 256, 256, 0, stream>>>(W1, w1h, w1l, 512, 256, 256);
    k_cvt_wT<<<(256 * 256 + 255) / 256, 256, 0, stream>>>(W2, w2h, w2l, 256, 256, 256);
    k_cvt_wT<<<(64 * 256 + 255) / 256, 256, 0, stream>>>(W3, w3h, w3l, 256, 60, 64);

    const int MB = (N_NODES + 127) / 128;   // 391
    const int GB = (N_NODES + 3) / 4;       // 12500

    // layer 1
    k_gemm_n256<true><<<dim3(1, MB), 512, 0, stream>>>(x, nullptr, nullptr, w1h, w1l,
                                                       H, N_NODES, F_IN);
    k_gather256<<<GB, 256, 0, stream>>>(H, row_ptr, esrc, dis, b1, Ghi, Glo);
    // layer 2
    k_gemm_n256<false><<<dim3(1, MB), 512, 0, stream>>>(nullptr, Ghi, Glo, w2h, w2l,
                                                        H, N_NODES, F_HID);
    k_gather256<<<GB, 256, 0, stream>>>(H, row_ptr, esrc, dis, b2, Ghi, Glo);
    // layer 3 (pool identity, dropout identity)
    k_gemm_n64<<<dim3(1, MB), 256, 0, stream>>>(Ghi, Glo, w3h, w3l, H3, N_NODES, F_OUT, F_HID);
    k_gather60<<<GB, 256, 0, stream>>>(H3, row_ptr, esrc, dis, b3, out);
}